// Round 3
// baseline (353.675 us; speedup 1.0000x reference)
//
#include <hip/hip_runtime.h>
#include <hip/hip_bf16.h>
#include <stdint.h>

typedef short   s16x8  __attribute__((ext_vector_type(8)));
typedef float   f32x4a __attribute__((ext_vector_type(4)));
typedef unsigned short u16x4 __attribute__((ext_vector_type(4)));
typedef int     i32x4  __attribute__((ext_vector_type(4)));

#define D_IN   4096
#define D_OUT  4096
#define RANK   16
#define KEXT   4128   // 4096 + 16 (lora) + 16 (zero pad); 129 * 32
#define MROWS  8192   // 4 * 2048
#define NT     (KEXT / 32)   // 129 K-tiles
#define LDS_TILE (256 * 32)  // elems per matrix per buffer (16 KB)

__device__ __forceinline__ uint16_t f32_to_bf16(float f) {
  union { float f; uint32_t u; } v; v.f = f;
  uint32_t u = v.u;
  return (uint16_t)((u + 0x7FFFu + ((u >> 16) & 1u)) >> 16);  // RNE
}

__device__ __forceinline__ void gload16(void* lds, const void* g) {
  __builtin_amdgcn_global_load_lds(
      (const __attribute__((address_space(1))) uint32_t*)g,
      (__attribute__((address_space(3))) uint32_t*)lds, 16, 0, 0);
}

// ---- 1) x fp32 -> bf16 into x_ext (row stride KEXT) --------------------
extern "C" __global__ void k_conv_x(const float* __restrict__ x,
                                    uint16_t* __restrict__ xext) {
  int64_t idx = (int64_t)blockIdx.x * blockDim.x + threadIdx.x;  // float4 index
  const int64_t total  = (int64_t)MROWS * (D_IN / 4);
  const int64_t stride = (int64_t)gridDim.x * blockDim.x;
  for (; idx < total; idx += stride) {
    int64_t m = idx >> 10;              // D_IN/4 = 1024
    int k4 = (int)(idx & 1023);
    f32x4a v = *(const f32x4a*)(x + m * D_IN + (int64_t)k4 * 4);
    u16x4 o;
#pragma unroll
    for (int j = 0; j < 4; j++) o[j] = f32_to_bf16(v[j]);
    *(u16x4*)(xext + m * KEXT + k4 * 4) = o;
  }
}

// ---- 2) xA = x_bf16 @ loraA^T via MFMA, into x_ext cols [4096,4128) ----
extern "C" __global__ __launch_bounds__(256) void k_xa(
    const uint16_t* __restrict__ xext_ro, uint16_t* __restrict__ xext_rw,
    const float* __restrict__ loraA) {
  const int tid = threadIdx.x, w = tid >> 6, l = tid & 63;
  const int l15 = l & 15, lk = l >> 4;
  const int64_t row0 = (int64_t)blockIdx.x * 64 + w * 16;
  f32x4a acc = {0.f, 0.f, 0.f, 0.f};
  const uint16_t* xrow = xext_ro + (row0 + l15) * KEXT + lk * 8;
  const float*    arow = loraA + (int64_t)l15 * D_IN + lk * 8;
  for (int k0 = 0; k0 < D_IN; k0 += 32) {
    s16x8 af = *(const s16x8*)(xrow + k0);
    s16x8 bf;
#pragma unroll
    for (int j = 0; j < 8; j++) bf[j] = (short)f32_to_bf16(arow[k0 + j]);
    acc = __builtin_amdgcn_mfma_f32_16x16x32_bf16(af, bf, acc, 0, 0, 0);
  }
#pragma unroll
  for (int reg = 0; reg < 4; reg++) {
    int64_t m = row0 + lk * 4 + reg;
    xext_rw[m * KEXT + D_IN + l15]        = f32_to_bf16(acc[reg]);
    xext_rw[m * KEXT + D_IN + RANK + l15] = (uint16_t)0;  // zero pad
  }
}

// ---- 3) qweight int -> bf16 + LoRA-B tail into w_ext -------------------
extern "C" __global__ void k_conv_w(const int* __restrict__ qw,
                                    const int* __restrict__ qscale,
                                    const float* __restrict__ meta,
                                    const float* __restrict__ loraB,
                                    uint16_t* __restrict__ wext) {
  const int n = blockIdx.x, t = threadIdx.x;
  const int* row  = qw   + (int64_t)n * D_IN;
  uint16_t*  orow = wext + (int64_t)n * KEXT;
  const int base = t * 16;
#pragma unroll
  for (int j = 0; j < 4; j++) {
    i32x4 v = *(const i32x4*)(row + base + j * 4);
    u16x4 o;
#pragma unroll
    for (int e = 0; e < 4; e++) o[e] = f32_to_bf16((float)v[e]);  // exact
    *(u16x4*)(orow + base + j * 4) = o;
  }
  if (t < RANK) {
    float sr = (float)qscale[n] * meta[0];
    orow[D_IN + t] = f32_to_bf16(2.0f * loraB[n * RANK + t] / sr);
  } else if (t < 2 * RANK) {
    orow[D_IN + t] = (uint16_t)0;  // zero pad
  }
}

// ---- 4) main GEMM: C = Xext @ Wext^T, 256x256 tile, BK=32 --------------
// 8 waves (2m x 4n), per-wave 128x64 out. 3 rotating LDS buffers; tile t+2
// staged (global_load_lds w=16) during tile t. ONE barrier + counted
// vmcnt(4) per K-tile: stage writes hit buffer (kt+2)%3, reads hit kt%3 ->
// no intra-tile hazard; end-of-tile barrier protects buffer (kt+3)%3=kt%3
// before next iteration stages into it. Waves drift within the tile so
// LDS drain overlaps other waves' MFMA.
extern "C" __global__ __launch_bounds__(512, 2) void k_gemm(
    const uint16_t* __restrict__ A, const uint16_t* __restrict__ B,
    const int* __restrict__ qscale, const float* __restrict__ meta,
    const float* __restrict__ bias, float* __restrict__ out) {
  extern __shared__ uint16_t lds[];            // 96 KB dynamic
  uint16_t* ldsA = lds;                        // [3][LDS_TILE]
  uint16_t* ldsB = lds + 3 * LDS_TILE;

  const int tid = threadIdx.x;
  const int bid = blockIdx.x;                  // 512 blocks, 512%8==0
  const int xcd = bid & 7, loc = bid >> 3;     // bijective XCD swizzle
  const int mtile = xcd * 4 + (loc & 3);       // 0..31
  const int ntile = loc >> 2;                  // 0..15

  const int w = tid >> 6, l = tid & 63;
  const int wm = w >> 2, wn = w & 3;
  const int l15 = l & 15, lk = l >> 4;

  const uint16_t* Ag = A + (int64_t)mtile * 256 * KEXT;
  const uint16_t* Bg = B + (int64_t)ntile * 256 * KEXT;

  // staging map: granule g -> (row, kchunk): row = ((g>>6)<<4)|(g&15),
  // kchunk = (g>>4)&3; dest byte = g*16 (linear in lane).
  const int row0 = ((tid >> 6) << 4) | (tid & 15);
  const int lk0  = (tid >> 4) & 3;
  const int64_t soff0 = (int64_t)row0 * KEXT + lk0 * 8;
  const int64_t soff1 = soff0 + (int64_t)128 * KEXT;
  const int dst0 = tid * 16, dst1 = dst0 + 8192;

#define STAGE_A(bi, kt) { char* p_ = (char*)(ldsA + (bi) * LDS_TILE); \
    gload16(p_ + dst0, Ag + (int64_t)(kt) * 32 + soff0);              \
    gload16(p_ + dst1, Ag + (int64_t)(kt) * 32 + soff1); }
#define STAGE_B(bi, kt) { char* p_ = (char*)(ldsB + (bi) * LDS_TILE); \
    gload16(p_ + dst0, Bg + (int64_t)(kt) * 32 + soff0);              \
    gload16(p_ + dst1, Bg + (int64_t)(kt) * 32 + soff1); }

  // fragment byte offset within a tile: element (row, kchunk lk) lives at
  // (row>>4)*1024 + lk*256 + (row&15)*16
  const int fro = lk * 256 + l15 * 16;

  f32x4a acc[8][4];
#pragma unroll
  for (int i = 0; i < 8; i++)
#pragma unroll
    for (int j = 0; j < 4; j++) acc[i][j] = (f32x4a){0.f, 0.f, 0.f, 0.f};

  // prologue: stage tiles 0 and 1; wait tile 0 (tile 1 stays in flight)
  STAGE_A(0, 0); STAGE_B(0, 0);
  STAGE_A(1, 1); STAGE_B(1, 1);
  asm volatile("s_waitcnt vmcnt(4)" ::: "memory");
  asm volatile("s_barrier" ::: "memory");

  int cur = 0;
  for (int kt = 0; kt < NT; ++kt) {
    const int b2 = (cur >= 1) ? cur - 1 : 2;   // (kt+2)%3
    const bool st = (kt + 2 < NT);
    const char* cA = (const char*)(ldsA + cur * LDS_TILE);
    const char* cB = (const char*)(ldsB + cur * LDS_TILE);

    if (st) { STAGE_A(b2, kt + 2); STAGE_B(b2, kt + 2); }

    s16x8 bf[4], af[8];
#pragma unroll
    for (int ni = 0; ni < 4; ++ni)
      bf[ni] = *(const s16x8*)(cB + (wn * 4 + ni) * 1024 + fro);
#pragma unroll
    for (int mi = 0; mi < 8; ++mi)
      af[mi] = *(const s16x8*)(cA + (wm * 8 + mi) * 1024 + fro);

    __builtin_amdgcn_s_setprio(1);
#pragma unroll
    for (int mi = 0; mi < 8; ++mi)
#pragma unroll
      for (int ni = 0; ni < 4; ++ni)
        acc[mi][ni] = __builtin_amdgcn_mfma_f32_16x16x32_bf16(
            af[mi], bf[ni], acc[mi][ni], 0, 0, 0);
    __builtin_amdgcn_s_setprio(0);

    // end-of-tile: keep tile t+2's 4 loads in flight (counted, never 0
    // in steady state); barrier releases buffer kt%3 for the next stage.
    if (st)                asm volatile("s_waitcnt vmcnt(4)" ::: "memory");
    else if (kt + 1 < NT)  asm volatile("s_waitcnt vmcnt(0)" ::: "memory");
    asm volatile("s_barrier" ::: "memory");

    cur = (cur == 2) ? 0 : cur + 1;
  }

  // epilogue: out = acc * (qscale[n]*meta) + bias[n]
  const float mv = meta[0];
  const int64_t mrow0 = (int64_t)mtile * 256 + wm * 128;
  const int ncol0 = ntile * 256 + wn * 64;
#pragma unroll
  for (int ni = 0; ni < 4; ++ni) {
    int n = ncol0 + ni * 16 + l15;
    float sr = (float)qscale[n] * mv;
    float bv = bias[n];
#pragma unroll
    for (int mi = 0; mi < 8; ++mi) {
      float* op = out + (mrow0 + mi * 16 + lk * 4) * (int64_t)D_OUT + n;
#pragma unroll
      for (int reg = 0; reg < 4; reg++)
        op[(int64_t)reg * D_OUT] = acc[mi][ni][reg] * sr + bv;
    }
  }
#undef STAGE_A
#undef STAGE_B
}

extern "C" void kernel_launch(void* const* d_in, const int* in_sizes, int n_in,
                              void* d_out, int out_size, void* d_ws, size_t ws_size,
                              hipStream_t stream) {
  const float* x    = (const float*)d_in[0];
  const int*   qw   = (const int*)d_in[1];
  const int*   qs   = (const int*)d_in[2];
  const float* meta = (const float*)d_in[3];
  const float* bias = (const float*)d_in[4];
  const float* lA   = (const float*)d_in[5];
  const float* lB   = (const float*)d_in[6];
  float* out = (float*)d_out;

  uint16_t* xext = (uint16_t*)d_ws;                       // 8192*4128*2 B
  uint16_t* wext = xext + (size_t)MROWS * KEXT;           // 4096*4128*2 B
  const size_t need = ((size_t)MROWS + D_OUT) * KEXT * 2; // 101,449,728 B
  if (ws_size < need) return;

  const int lds_bytes = 6 * LDS_TILE * 2;                 // 96 KB
  (void)hipFuncSetAttribute((const void*)k_gemm,
                            hipFuncAttributeMaxDynamicSharedMemorySize,
                            lds_bytes);

  k_conv_x<<<2048, 256, 0, stream>>>(x, xext);
  k_xa<<<MROWS / 64, 256, 0, stream>>>(xext, xext, lA);
  k_conv_w<<<D_OUT, 256, 0, stream>>>(qw, qs, meta, lB, wext);
  k_gemm<<<512, 512, lds_bytes, stream>>>(xext, wext, qs, meta, bias, out);
}

// Round 4
// 345.202 us; speedup vs baseline: 1.0245x; 1.0245x over previous
//
#include <hip/hip_runtime.h>
#include <hip/hip_bf16.h>
#include <stdint.h>

typedef short   s16x8  __attribute__((ext_vector_type(8)));
typedef float   f32x4a __attribute__((ext_vector_type(4)));
typedef unsigned short u16x4 __attribute__((ext_vector_type(4)));
typedef int     i32x4  __attribute__((ext_vector_type(4)));

#define D_IN   4096
#define D_OUT  4096
#define RANK   16
#define KEXT   4128   // 4096 + 16 (lora) + 16 (zero pad)
#define MROWS  8192   // 4 * 2048
#define NT64   64     // main K-tiles of 64; tail = 32 (lora+pad)

__device__ __forceinline__ uint16_t f32_to_bf16(float f) {
  union { float f; uint32_t u; } v; v.f = f;
  uint32_t u = v.u;
  return (uint16_t)((u + 0x7FFFu + ((u >> 16) & 1u)) >> 16);  // RNE
}

__device__ __forceinline__ void gload16(void* lds, const void* g) {
  __builtin_amdgcn_global_load_lds(
      (const __attribute__((address_space(1))) uint32_t*)g,
      (__attribute__((address_space(3))) uint32_t*)lds, 16, 0, 0);
}

// ---- 1) x fp32 -> bf16 into x_ext (row stride KEXT) --------------------
extern "C" __global__ void k_conv_x(const float* __restrict__ x,
                                    uint16_t* __restrict__ xext) {
  int64_t idx = (int64_t)blockIdx.x * blockDim.x + threadIdx.x;  // float4 index
  const int64_t total  = (int64_t)MROWS * (D_IN / 4);
  const int64_t stride = (int64_t)gridDim.x * blockDim.x;
  for (; idx < total; idx += stride) {
    int64_t m = idx >> 10;              // D_IN/4 = 1024
    int k4 = (int)(idx & 1023);
    f32x4a v = *(const f32x4a*)(x + m * D_IN + (int64_t)k4 * 4);
    u16x4 o;
#pragma unroll
    for (int j = 0; j < 4; j++) o[j] = f32_to_bf16(v[j]);
    *(u16x4*)(xext + m * KEXT + k4 * 4) = o;
  }
}

// ---- 2) xA = x_bf16 @ loraA^T via MFMA, into x_ext cols [4096,4128) ----
extern "C" __global__ __launch_bounds__(256) void k_xa(
    const uint16_t* __restrict__ xext_ro, uint16_t* __restrict__ xext_rw,
    const float* __restrict__ loraA) {
  const int tid = threadIdx.x, w = tid >> 6, l = tid & 63;
  const int l15 = l & 15, lk = l >> 4;
  const int64_t row0 = (int64_t)blockIdx.x * 64 + w * 16;
  f32x4a acc = {0.f, 0.f, 0.f, 0.f};
  const uint16_t* xrow = xext_ro + (row0 + l15) * KEXT + lk * 8;
  const float*    arow = loraA + (int64_t)l15 * D_IN + lk * 8;
  for (int k0 = 0; k0 < D_IN; k0 += 32) {
    s16x8 af = *(const s16x8*)(xrow + k0);
    s16x8 bf;
#pragma unroll
    for (int j = 0; j < 8; j++) bf[j] = (short)f32_to_bf16(arow[k0 + j]);
    acc = __builtin_amdgcn_mfma_f32_16x16x32_bf16(af, bf, acc, 0, 0, 0);
  }
#pragma unroll
  for (int reg = 0; reg < 4; reg++) {
    int64_t m = row0 + lk * 4 + reg;
    xext_rw[m * KEXT + D_IN + l15]        = f32_to_bf16(acc[reg]);
    xext_rw[m * KEXT + D_IN + RANK + l15] = (uint16_t)0;  // zero pad
  }
}

// ---- 3) qweight int -> bf16 + LoRA-B tail into w_ext -------------------
extern "C" __global__ void k_conv_w(const int* __restrict__ qw,
                                    const int* __restrict__ qscale,
                                    const float* __restrict__ meta,
                                    const float* __restrict__ loraB,
                                    uint16_t* __restrict__ wext) {
  const int n = blockIdx.x, t = threadIdx.x;
  const int* row  = qw   + (int64_t)n * D_IN;
  uint16_t*  orow = wext + (int64_t)n * KEXT;
  const int base = t * 16;
#pragma unroll
  for (int j = 0; j < 4; j++) {
    i32x4 v = *(const i32x4*)(row + base + j * 4);
    u16x4 o;
#pragma unroll
    for (int e = 0; e < 4; e++) o[e] = f32_to_bf16((float)v[e]);  // exact
    *(u16x4*)(orow + base + j * 4) = o;
  }
  if (t < RANK) {
    float sr = (float)qscale[n] * meta[0];
    orow[D_IN + t] = f32_to_bf16(2.0f * loraB[n * RANK + t] / sr);
  } else if (t < 2 * RANK) {
    orow[D_IN + t] = (uint16_t)0;  // zero pad
  }
}

// ---- 4) main GEMM: 256x256 tile, BK=64, 8-phase counted-vmcnt ----------
// 8 waves (2m x 4n), per-wave 128x64. LDS 128 KB: A/B x 2 dbuf x 32 KB,
// layout [kc][rb][lane][16B] (gload dest linear, ds_read contiguous).
// Per K-tile: 4 phases x {ds_read 4/8 frag; stage 1 half-tile (2 gload);
// barrier; lgkmcnt(0); setprio(1) 16 MFMA setprio(0); [vmcnt(4) at P1/P3];
// barrier}. Halves split by k so staging order == consumption order;
// steady-state vmcnt never drains to 0. Tail (K=32, lora) = one half-tile.
extern "C" __global__ __launch_bounds__(512, 2) void k_gemm(
    const uint16_t* __restrict__ A, const uint16_t* __restrict__ B,
    const int* __restrict__ qscale, const float* __restrict__ meta,
    const float* __restrict__ bias, float* __restrict__ out) {
  extern __shared__ char ldsc[];               // 131072 B
  char* aB = ldsc;                             // [2][32768]
  char* bB = ldsc + 65536;                     // [2][32768]

  const int tid = threadIdx.x;
  const int bid = blockIdx.x;                  // 512 blocks, 512%8==0
  const int xcd = bid & 7, loc = bid >> 3;
  const int mtile = xcd * 4 + (loc & 3);       // 0..31
  const int ntile = loc >> 2;                  // 0..15

  const int w = tid >> 6, l = tid & 63;
  const int wm = w >> 2, wn = w & 3;
  const int l15 = l & 15, lk = l >> 4;
  const int fro = lk * 256 + l15 * 16;         // frag byte offset in 1024-B run

  const uint16_t* Ag = A + (int64_t)mtile * 256 * KEXT;
  const uint16_t* Bg = B + (int64_t)ntile * 256 * KEXT;

  // staging: slot s -> kc=s>>10, rb=(s>>6)&15, lk=(s>>4)&3, l15=s&15
  // call pattern gives linear LDS dest (base + lane*16) per wave.
  const int row_lo = ((tid >> 6) << 4) | (tid & 15);           // 0..127
  const int64_t s_lo = (int64_t)row_lo * KEXT + ((tid >> 4) & 3) * 8;
  const int64_t s_hi = s_lo + (int64_t)128 * KEXT;

#define STG_K0(bufp, gp, kb) {                                      \
    gload16((bufp) + (size_t)tid * 16,        (gp) + (kb) + s_lo);  \
    gload16((bufp) + (size_t)(512 + tid) * 16,(gp) + (kb) + s_hi); }
#define STG_K1(bufp, gp, kb) {                                           \
    gload16((bufp) + (size_t)(1024 + tid) * 16,(gp) + (kb) + 32 + s_lo); \
    gload16((bufp) + (size_t)(1536 + tid) * 16,(gp) + (kb) + 32 + s_hi); }

  f32x4a acc[8][4];
#pragma unroll
  for (int i = 0; i < 8; i++)
#pragma unroll
    for (int j = 0; j < 4; j++) acc[i][j] = (f32x4a){0.f, 0.f, 0.f, 0.f};

  // prologue: tile0 k0-halves (4 loads) then k1-halves (4); wait k0.
  STG_K0(aB, Ag, 0); STG_K0(bB, Bg, 0);
  STG_K1(aB, Ag, 0); STG_K1(bB, Bg, 0);
  asm volatile("s_waitcnt vmcnt(4)" ::: "memory");
  asm volatile("s_barrier" ::: "memory");

  s16x8 bf[4];

#define PHASE(MH, KC, STAGE_STMT, WAIT_STMT) {                               \
    s16x8 af[4];                                                             \
    _Pragma("unroll")                                                        \
    for (int mi = 0; mi < 4; ++mi)                                           \
      af[mi] = *(const s16x8*)(cA + (KC) * 16384 +                           \
                               (wm * 8 + (MH) * 4 + mi) * 1024 + fro);       \
    if ((MH) == 0) {                                                         \
      _Pragma("unroll")                                                      \
      for (int ni = 0; ni < 4; ++ni)                                         \
        bf[ni] = *(const s16x8*)(cB + (KC) * 16384 +                         \
                                 (wn * 4 + ni) * 1024 + fro);                \
    }                                                                        \
    STAGE_STMT;                                                              \
    asm volatile("s_barrier" ::: "memory");                                  \
    asm volatile("s_waitcnt lgkmcnt(0)" ::: "memory");                       \
    __builtin_amdgcn_s_setprio(1);                                           \
    _Pragma("unroll")                                                        \
    for (int mi = 0; mi < 4; ++mi)                                           \
      _Pragma("unroll")                                                      \
      for (int ni = 0; ni < 4; ++ni)                                         \
        acc[(MH) * 4 + mi][ni] = __builtin_amdgcn_mfma_f32_16x16x32_bf16(    \
            af[mi], bf[ni], acc[(MH) * 4 + mi][ni], 0, 0, 0);                \
    __builtin_amdgcn_s_setprio(0);                                           \
    WAIT_STMT;                                                               \
    asm volatile("s_barrier" ::: "memory"); }

  for (int kt = 0; kt < NT64; ++kt) {
    const int cur = kt & 1;
    const char* cA = aB + cur * 32768;
    const char* cB = bB + cur * 32768;
    char* nA = aB + (cur ^ 1) * 32768;   // kt==63: (63&1)^1=0 -> tail in buf0
    char* nB = bB + (cur ^ 1) * 32768;
    const int64_t kb = (int64_t)(kt + 1) * 64;   // kt==63 -> 4096 = lora tail
    const bool full = (kt < NT64 - 1);

    PHASE(0, 0, STG_K0(nA, Ag, kb), )
    PHASE(1, 0, STG_K0(nB, Bg, kb),
          asm volatile("s_waitcnt vmcnt(4)" ::: "memory");)
    PHASE(0, 1, if (full) STG_K1(nA, Ag, kb), )
    PHASE(1, 1, if (full) STG_K1(nB, Bg, kb),
          if (full) { asm volatile("s_waitcnt vmcnt(4)" ::: "memory"); }
          else      { asm volatile("s_waitcnt vmcnt(0)" ::: "memory"); })
  }

  // ---- LoRA tail: K = 32 (cols 4096..4127), buf0 kc=0, no sync needed ----
  {
    const char* cA = aB;
    const char* cB = bB;
    s16x8 tf[4];
#pragma unroll
    for (int ni = 0; ni < 4; ++ni)
      tf[ni] = *(const s16x8*)(cB + (wn * 4 + ni) * 1024 + fro);
#pragma unroll
    for (int mh = 0; mh < 2; ++mh) {
      s16x8 af[4];
#pragma unroll
      for (int mi = 0; mi < 4; ++mi)
        af[mi] = *(const s16x8*)(cA + (wm * 8 + mh * 4 + mi) * 1024 + fro);
#pragma unroll
      for (int mi = 0; mi < 4; ++mi)
#pragma unroll
        for (int ni = 0; ni < 4; ++ni)
          acc[mh * 4 + mi][ni] = __builtin_amdgcn_mfma_f32_16x16x32_bf16(
              af[mi], tf[ni], acc[mh * 4 + mi][ni], 0, 0, 0);
    }
  }

  // epilogue: out = acc * (qscale[n]*meta) + bias[n]
  const float mv = meta[0];
  const int64_t mrow0 = (int64_t)mtile * 256 + wm * 128;
  const int ncol0 = ntile * 256 + wn * 64;
#pragma unroll
  for (int ni = 0; ni < 4; ++ni) {
    int n = ncol0 + ni * 16 + l15;
    float sr = (float)qscale[n] * mv;
    float bv = bias[n];
#pragma unroll
    for (int mi = 0; mi < 8; ++mi) {
      float* op = out + (mrow0 + mi * 16 + lk * 4) * (int64_t)D_OUT + n;
#pragma unroll
      for (int reg = 0; reg < 4; reg++)
        op[(int64_t)reg * D_OUT] = acc[mi][ni][reg] * sr + bv;
    }
  }
#undef PHASE
#undef STG_K0
#undef STG_K1
}

extern "C" void kernel_launch(void* const* d_in, const int* in_sizes, int n_in,
                              void* d_out, int out_size, void* d_ws, size_t ws_size,
                              hipStream_t stream) {
  const float* x    = (const float*)d_in[0];
  const int*   qw   = (const int*)d_in[1];
  const int*   qs   = (const int*)d_in[2];
  const float* meta = (const float*)d_in[3];
  const float* bias = (const float*)d_in[4];
  const float* lA   = (const float*)d_in[5];
  const float* lB   = (const float*)d_in[6];
  float* out = (float*)d_out;

  uint16_t* xext = (uint16_t*)d_ws;                       // 8192*4128*2 B
  uint16_t* wext = xext + (size_t)MROWS * KEXT;           // 4096*4128*2 B
  const size_t need = ((size_t)MROWS + D_OUT) * KEXT * 2; // 101,449,728 B
  if (ws_size < need) return;

  const int lds_bytes = 131072;                           // 128 KB
  (void)hipFuncSetAttribute((const void*)k_gemm,
                            hipFuncAttributeMaxDynamicSharedMemorySize,
                            lds_bytes);

  k_conv_x<<<2048, 256, 0, stream>>>(x, xext);
  k_xa<<<MROWS / 64, 256, 0, stream>>>(xext, xext, lA);
  k_conv_w<<<D_OUT, 256, 0, stream>>>(qw, qs, meta, lB, wext);
  k_gemm<<<512, 512, lds_bytes, stream>>>(xext, wext, qs, meta, bias, out);
}